// Round 1
// baseline (400.730 us; speedup 1.0000x reference)
//
#include <hip/hip_runtime.h>
#include <math.h>

constexpr int D = 128;       // in_channels
constexpr int B = 512;       // batch_size (graphs)
constexpr int STEPS = 3;

// ---------------------------------------------------------------------------
// K0: segment bounds via binary search on sorted batch[]. seg[g] = first index
// with batch[i] >= g, for g in [0, B]; graph g owns [seg[g], seg[g+1]).
// ---------------------------------------------------------------------------
__global__ void k_bounds(const int* __restrict__ batch, int n, int* __restrict__ seg) {
    int g = blockIdx.x * blockDim.x + threadIdx.x;
    if (g > B) return;
    int lo = 0, hi = n;
    while (lo < hi) {
        int mid = (lo + hi) >> 1;
        if (batch[mid] < g) lo = mid + 1; else hi = mid;
    }
    seg[g] = lo;
}

__device__ __forceinline__ float sigmoidf_(float x) { return 1.f / (1.f + __expf(-x)); }

// ---------------------------------------------------------------------------
// K1: GRU cell. h_new = GRU(q_star, h). One block = 4 graphs, 128 threads;
// thread t computes output dim t for all 4 graphs (gate rows t, 128+t, 256+t).
// Also writes q-part of q_star (cols 0..127) = h_new.
// W reads are L2-resident (590 KB total weights).
// ---------------------------------------------------------------------------
__global__ __launch_bounds__(128) void k_gru(float* qstar, float* h,
        const float* __restrict__ Wih, const float* __restrict__ Whh,
        const float* __restrict__ bih, const float* __restrict__ bhh) {
    __shared__ float s_q[4][2 * D];
    __shared__ float s_h[4][D];
    const int t = threadIdx.x;
    const int b0 = blockIdx.x * 4;
#pragma unroll
    for (int g = 0; g < 4; ++g) {
        s_q[g][t]       = qstar[(b0 + g) * (2 * D) + t];
        s_q[g][t + D]   = qstar[(b0 + g) * (2 * D) + D + t];
        s_h[g][t]       = h[(b0 + g) * D + t];
    }
    __syncthreads();

    float gi_r[4], gi_z[4], gi_n[4], gh_r[4], gh_z[4], gh_n[4];
#pragma unroll
    for (int g = 0; g < 4; ++g) {
        gi_r[g] = bih[t];       gi_z[g] = bih[D + t];   gi_n[g] = bih[2 * D + t];
        gh_r[g] = bhh[t];       gh_z[g] = bhh[D + t];   gh_n[g] = bhh[2 * D + t];
    }

    const float4* Wr = (const float4*)(Wih + (size_t)t * (2 * D));
    const float4* Wz = (const float4*)(Wih + (size_t)(D + t) * (2 * D));
    const float4* Wn = (const float4*)(Wih + (size_t)(2 * D + t) * (2 * D));
    for (int k4 = 0; k4 < (2 * D) / 4; ++k4) {
        float4 wr = Wr[k4], wz = Wz[k4], wn = Wn[k4];
#pragma unroll
        for (int g = 0; g < 4; ++g) {
            const float* q = &s_q[g][k4 * 4];
            gi_r[g] += wr.x * q[0] + wr.y * q[1] + wr.z * q[2] + wr.w * q[3];
            gi_z[g] += wz.x * q[0] + wz.y * q[1] + wz.z * q[2] + wz.w * q[3];
            gi_n[g] += wn.x * q[0] + wn.y * q[1] + wn.z * q[2] + wn.w * q[3];
        }
    }
    const float4* Vr = (const float4*)(Whh + (size_t)t * D);
    const float4* Vz = (const float4*)(Whh + (size_t)(D + t) * D);
    const float4* Vn = (const float4*)(Whh + (size_t)(2 * D + t) * D);
    for (int k4 = 0; k4 < D / 4; ++k4) {
        float4 wr = Vr[k4], wz = Vz[k4], wn = Vn[k4];
#pragma unroll
        for (int g = 0; g < 4; ++g) {
            const float* hh = &s_h[g][k4 * 4];
            gh_r[g] += wr.x * hh[0] + wr.y * hh[1] + wr.z * hh[2] + wr.w * hh[3];
            gh_z[g] += wz.x * hh[0] + wz.y * hh[1] + wz.z * hh[2] + wz.w * hh[3];
            gh_n[g] += wn.x * hh[0] + wn.y * hh[1] + wn.z * hh[2] + wn.w * hh[3];
        }
    }

#pragma unroll
    for (int g = 0; g < 4; ++g) {
        float r = sigmoidf_(gi_r[g] + gh_r[g]);
        float z = sigmoidf_(gi_z[g] + gh_z[g]);
        float nn = tanhf(gi_n[g] + r * gh_n[g]);
        float hn = (1.f - z) * nn + z * s_h[g][t];
        h[(b0 + g) * D + t] = hn;
        qstar[(b0 + g) * (2 * D) + t] = hn;   // q part of output
    }
}

// ---------------------------------------------------------------------------
// K2: segment-softmax attention, one block per graph, 256 threads (8 half-waves).
// Each half-wave (32 lanes) handles one node per iter: float4/lane -> dot with
// q fragment -> 5-step xor reduce. Pass 1: e + online (m,l). Pass 2: r += a*x.
// ---------------------------------------------------------------------------
__global__ __launch_bounds__(256) void k_attn(const float* __restrict__ x,
        const float* __restrict__ h, const int* __restrict__ seg,
        float* __restrict__ e_buf, float* qstar) {
    const int b = blockIdx.x;
    const int start = seg[b], end = seg[b + 1];
    const int tid = threadIdx.x;
    const int lane32 = tid & 31;
    const int hw = tid >> 5;          // half-wave id 0..7

    const float4 qf = ((const float4*)(h + (size_t)b * D))[lane32];

    // ---- pass 1: e_i = <x_i, q_b>, online max/sumexp ----
    float m_run = -INFINITY, l_run = 0.f;
    for (int node = start + hw; node < end; node += 8) {
        float4 xv = ((const float4*)(x + (size_t)node * D))[lane32];
        float p = xv.x * qf.x + xv.y * qf.y + xv.z * qf.z + xv.w * qf.w;
        p += __shfl_xor(p, 16, 64);
        p += __shfl_xor(p, 8, 64);
        p += __shfl_xor(p, 4, 64);
        p += __shfl_xor(p, 2, 64);
        p += __shfl_xor(p, 1, 64);
        if (lane32 == 0) e_buf[node] = p;
        float nm = fmaxf(m_run, p);
        l_run = l_run * __expf(m_run - nm) + __expf(p - nm);
        m_run = nm;
    }

    __shared__ float sm[8], sl[8];
    __shared__ float s_M, s_inv;
    if (lane32 == 0) { sm[hw] = m_run; sl[hw] = l_run; }
    __syncthreads();
    if (tid == 0) {
        float M = -INFINITY;
        for (int i = 0; i < 8; ++i) M = fmaxf(M, sm[i]);
        float L = 0.f;
        for (int i = 0; i < 8; ++i)
            L += (sm[i] == -INFINITY) ? 0.f : sl[i] * __expf(sm[i] - M);
        s_M = M;
        s_inv = 1.f / (L + 1e-16f);
    }
    __syncthreads();
    const float M = s_M;
    const float inv = s_inv;

    // ---- pass 2: r_b = sum a_i * x_i ----
    float4 acc = {0.f, 0.f, 0.f, 0.f};
    for (int node = start + hw; node < end; node += 8) {
        float4 xv = ((const float4*)(x + (size_t)node * D))[lane32];
        float a = __expf(e_buf[node] - M) * inv;
        acc.x += a * xv.x; acc.y += a * xv.y; acc.z += a * xv.z; acc.w += a * xv.w;
    }
    // fold second half-wave onto first within each wave
    acc.x += __shfl_down(acc.x, 32, 64);
    acc.y += __shfl_down(acc.y, 32, 64);
    acc.z += __shfl_down(acc.z, 32, 64);
    acc.w += __shfl_down(acc.w, 32, 64);

    __shared__ float rpart[4][D];
    const int wave = tid >> 6;
    const int lane64 = tid & 63;
    if (lane64 < 32) ((float4*)rpart[wave])[lane64] = acc;
    __syncthreads();
    if (tid < D) {
        float v = rpart[0][tid] + rpart[1][tid] + rpart[2][tid] + rpart[3][tid];
        qstar[(size_t)b * (2 * D) + D + tid] = v;   // r part of output
    }
}

// ---------------------------------------------------------------------------
extern "C" void kernel_launch(void* const* d_in, const int* in_sizes, int n_in,
                              void* d_out, int out_size, void* d_ws, size_t ws_size,
                              hipStream_t stream) {
    const float* x    = (const float*)d_in[0];
    const int*   batch= (const int*)d_in[1];
    // d_in[2] = batch_size scalar (fixed at B=512 compile time)
    const float* Wih  = (const float*)d_in[3];
    const float* Whh  = (const float*)d_in[4];
    const float* bih  = (const float*)d_in[5];
    const float* bhh  = (const float*)d_in[6];
    const int n = in_sizes[0] / D;        // 200000

    float* qstar = (float*)d_out;         // [B, 2D] — doubles as iteration state

    // workspace layout: seg (4 KB) | h (256 KB) | e_buf (n*4 B)
    char* ws = (char*)d_ws;
    int*   seg   = (int*)ws;
    float* h     = (float*)(ws + 4096);
    float* e_buf = (float*)(ws + 4096 + (size_t)B * D * sizeof(float));

    hipMemsetAsync(d_out, 0, (size_t)out_size * sizeof(float), stream);
    hipMemsetAsync(h, 0, (size_t)B * D * sizeof(float), stream);
    k_bounds<<<(B + 256) / 256, 256, 0, stream>>>(batch, n, seg);

    for (int s = 0; s < STEPS; ++s) {
        k_gru<<<B / 4, 128, 0, stream>>>(qstar, h, Wih, Whh, bih, bhh);
        k_attn<<<B, 256, 0, stream>>>(x, h, seg, e_buf, qstar);
    }
}

// Round 2
// 312.211 us; speedup vs baseline: 1.2835x; 1.2835x over previous
//
#include <hip/hip_runtime.h>
#include <math.h>

constexpr int D = 128;       // in_channels
constexpr int B = 512;       // batch_size (graphs)
constexpr int STEPS = 3;

// ---------------------------------------------------------------------------
// K0: segment bounds via binary search on sorted batch[]. seg[g] = first index
// with batch[i] >= g, for g in [0, B]; graph g owns [seg[g], seg[g+1]).
// ---------------------------------------------------------------------------
__global__ void k_bounds(const int* __restrict__ batch, int n, int* __restrict__ seg) {
    int g = blockIdx.x * blockDim.x + threadIdx.x;
    if (g > B) return;
    int lo = 0, hi = n;
    while (lo < hi) {
        int mid = (lo + hi) >> 1;
        if (batch[mid] < g) lo = mid + 1; else hi = mid;
    }
    seg[g] = lo;
}

__device__ __forceinline__ float sigmoidf_(float x) { return 1.f / (1.f + __expf(-x)); }

// ---------------------------------------------------------------------------
// K1: GRU cell, 4 graphs per block, 384 threads (6 waves; 3 waves/CU at 128
// blocks). Thread t computes gate-row t (r:0..127, z:128..255, n:256..383)
// for all 4 graphs; rows are exchanged via LDS for the elementwise epilogue.
// ---------------------------------------------------------------------------
__global__ __launch_bounds__(384) void k_gru(float* qstar, float* h,
        const float* __restrict__ Wih, const float* __restrict__ Whh,
        const float* __restrict__ bih, const float* __restrict__ bhh) {
    __shared__ float s_q[4][2 * D];      // 4 KB
    __shared__ float s_h[4][D];          // 2 KB
    __shared__ float s_gi[4][3 * D];     // 6 KB
    __shared__ float s_gh[4][3 * D];     // 6 KB
    const int t = threadIdx.x;           // 0..383 == gate row
    const int b0 = blockIdx.x * 4;

    // graphs b0..b0+3 are contiguous rows -> flat cooperative load
    for (int i = t; i < 4 * 2 * D; i += 384) ((float*)s_q)[i] = qstar[(size_t)b0 * 2 * D + i];
    for (int i = t; i < 4 * D; i += 384)     ((float*)s_h)[i] = h[(size_t)b0 * D + i];
    __syncthreads();

    float gi[4], gh[4];
#pragma unroll
    for (int g = 0; g < 4; ++g) { gi[g] = bih[t]; gh[g] = bhh[t]; }

    const float4* Wr = (const float4*)(Wih + (size_t)t * (2 * D));
    for (int k4 = 0; k4 < (2 * D) / 4; ++k4) {
        float4 w = Wr[k4];
#pragma unroll
        for (int g = 0; g < 4; ++g) {
            float4 q = *(const float4*)&s_q[g][k4 * 4];
            gi[g] = fmaf(w.x, q.x, fmaf(w.y, q.y, fmaf(w.z, q.z, fmaf(w.w, q.w, gi[g]))));
        }
    }
    const float4* Vr = (const float4*)(Whh + (size_t)t * D);
    for (int k4 = 0; k4 < D / 4; ++k4) {
        float4 w = Vr[k4];
#pragma unroll
        for (int g = 0; g < 4; ++g) {
            float4 hh = *(const float4*)&s_h[g][k4 * 4];
            gh[g] = fmaf(w.x, hh.x, fmaf(w.y, hh.y, fmaf(w.z, hh.z, fmaf(w.w, hh.w, gh[g]))));
        }
    }
#pragma unroll
    for (int g = 0; g < 4; ++g) { s_gi[g][t] = gi[g]; s_gh[g][t] = gh[g]; }
    __syncthreads();

    if (t < D) {
#pragma unroll
        for (int g = 0; g < 4; ++g) {
            float r  = sigmoidf_(s_gi[g][t]         + s_gh[g][t]);
            float z  = sigmoidf_(s_gi[g][D + t]     + s_gh[g][D + t]);
            float nn = tanhf    (s_gi[g][2 * D + t] + r * s_gh[g][2 * D + t]);
            float hn = (1.f - z) * nn + z * s_h[g][t];
            h[(size_t)(b0 + g) * D + t] = hn;
            qstar[(size_t)(b0 + g) * 2 * D + t] = hn;   // q part of output
        }
    }
}

// ---------------------------------------------------------------------------
// K2: segment-softmax attention. One block per graph, 1024 threads
// (32 half-waves, 16 waves) -> 2 blocks/CU = 32 waves/CU (full occupancy).
// Each half-wave handles one node/iter: float4/lane dot + 5-step xor reduce.
// Pass 1: e + online (m,l). Pass 2: r += a*x.
// ---------------------------------------------------------------------------
__global__ __launch_bounds__(1024) void k_attn(const float* __restrict__ x,
        const float* __restrict__ h, const int* __restrict__ seg,
        float* __restrict__ e_buf, float* qstar) {
    const int b = blockIdx.x;
    const int start = seg[b], end = seg[b + 1];
    const int tid = threadIdx.x;
    const int lane32 = tid & 31;
    const int hw = tid >> 5;          // half-wave id 0..31

    const float4 qf = ((const float4*)(h + (size_t)b * D))[lane32];

    // ---- pass 1: e_i = <x_i, q_b>, online max/sumexp ----
    float m_run = -INFINITY, l_run = 0.f;
    for (int node = start + hw; node < end; node += 32) {
        float4 xv = ((const float4*)(x + (size_t)node * D))[lane32];
        float p = fmaf(xv.x, qf.x, fmaf(xv.y, qf.y, fmaf(xv.z, qf.z, xv.w * qf.w)));
        p += __shfl_xor(p, 16, 64);
        p += __shfl_xor(p, 8, 64);
        p += __shfl_xor(p, 4, 64);
        p += __shfl_xor(p, 2, 64);
        p += __shfl_xor(p, 1, 64);
        if (lane32 == 0) e_buf[node] = p;
        float nm = fmaxf(m_run, p);
        l_run = l_run * __expf(m_run - nm) + __expf(p - nm);
        m_run = nm;
    }

    __shared__ float sm[32], sl[32];
    __shared__ float s_M, s_inv;
    if (lane32 == 0) { sm[hw] = m_run; sl[hw] = l_run; }
    __syncthreads();
    if (tid == 0) {
        float M = -INFINITY;
        for (int i = 0; i < 32; ++i) M = fmaxf(M, sm[i]);
        float L = 0.f;
        for (int i = 0; i < 32; ++i)
            L += (sm[i] == -INFINITY) ? 0.f : sl[i] * __expf(sm[i] - M);
        s_M = M;
        s_inv = 1.f / (L + 1e-16f);
    }
    __syncthreads();
    const float M = s_M;
    const float inv = s_inv;

    // ---- pass 2: r_b = sum a_i * x_i ----
    float4 acc = {0.f, 0.f, 0.f, 0.f};
    for (int node = start + hw; node < end; node += 32) {
        float4 xv = ((const float4*)(x + (size_t)node * D))[lane32];
        float a = __expf(e_buf[node] - M) * inv;
        acc.x = fmaf(a, xv.x, acc.x);
        acc.y = fmaf(a, xv.y, acc.y);
        acc.z = fmaf(a, xv.z, acc.z);
        acc.w = fmaf(a, xv.w, acc.w);
    }
    // fold upper half-wave onto lower within each 64-lane wave
    acc.x += __shfl_down(acc.x, 32, 64);
    acc.y += __shfl_down(acc.y, 32, 64);
    acc.z += __shfl_down(acc.z, 32, 64);
    acc.w += __shfl_down(acc.w, 32, 64);

    __shared__ float rpart[16][D];    // 8 KB
    const int wave = tid >> 6;        // 0..15
    const int lane64 = tid & 63;
    if (lane64 < 32) ((float4*)rpart[wave])[lane64] = acc;
    __syncthreads();
    if (tid < D) {
        float v = 0.f;
#pragma unroll
        for (int w = 0; w < 16; ++w) v += rpart[w][tid];
        qstar[(size_t)b * (2 * D) + D + tid] = v;   // r part of output
    }
}

// ---------------------------------------------------------------------------
extern "C" void kernel_launch(void* const* d_in, const int* in_sizes, int n_in,
                              void* d_out, int out_size, void* d_ws, size_t ws_size,
                              hipStream_t stream) {
    const float* x    = (const float*)d_in[0];
    const int*   batch= (const int*)d_in[1];
    // d_in[2] = batch_size scalar (fixed at B=512 compile time)
    const float* Wih  = (const float*)d_in[3];
    const float* Whh  = (const float*)d_in[4];
    const float* bih  = (const float*)d_in[5];
    const float* bhh  = (const float*)d_in[6];
    const int n = in_sizes[0] / D;        // 200000

    float* qstar = (float*)d_out;         // [B, 2D] — doubles as iteration state

    // workspace layout: seg (4 KB) | h (256 KB) | e_buf (n*4 B)
    char* ws = (char*)d_ws;
    int*   seg   = (int*)ws;
    float* h     = (float*)(ws + 4096);
    float* e_buf = (float*)(ws + 4096 + (size_t)B * D * sizeof(float));

    hipMemsetAsync(d_out, 0, (size_t)out_size * sizeof(float), stream);
    hipMemsetAsync(h, 0, (size_t)B * D * sizeof(float), stream);
    k_bounds<<<(B + 256) / 256, 256, 0, stream>>>(batch, n, seg);

    for (int s = 0; s < STEPS; ++s) {
        k_gru<<<B / 4, 384, 0, stream>>>(qstar, h, Wih, Whh, bih, bhh);
        k_attn<<<B, 1024, 0, stream>>>(x, h, seg, e_buf, qstar);
    }
}

// Round 3
// 275.544 us; speedup vs baseline: 1.4543x; 1.1331x over previous
//
#include <hip/hip_runtime.h>
#include <math.h>

constexpr int D = 128;       // in_channels
constexpr int B = 512;       // batch_size (graphs)
constexpr int STEPS = 3;

// ---------------------------------------------------------------------------
// K0: segment bounds via binary search on sorted batch[]. seg[g] = first index
// with batch[i] >= g, for g in [0, B]; graph g owns [seg[g], seg[g+1]).
// ---------------------------------------------------------------------------
__global__ void k_bounds(const int* __restrict__ batch, int n, int* __restrict__ seg) {
    int g = blockIdx.x * blockDim.x + threadIdx.x;
    if (g > B) return;
    int lo = 0, hi = n;
    while (lo < hi) {
        int mid = (lo + hi) >> 1;
        if (batch[mid] < g) lo = mid + 1; else hi = mid;
    }
    seg[g] = lo;
}

__device__ __forceinline__ float sigmoidf_(float x) { return 1.f / (1.f + __expf(-x)); }

// ---------------------------------------------------------------------------
// K1: GRU cell, 4 graphs per block, 384 threads. Thread t computes gate-row t
// (r:0..127, z:128..255, n:256..383) for all 4 graphs; rows exchanged via LDS
// for the elementwise epilogue. Weights are L2-resident (590 KB).
// ---------------------------------------------------------------------------
__global__ __launch_bounds__(384) void k_gru(float* qstar, float* h,
        const float* __restrict__ Wih, const float* __restrict__ Whh,
        const float* __restrict__ bih, const float* __restrict__ bhh) {
    __shared__ float s_q[4][2 * D];      // 4 KB
    __shared__ float s_h[4][D];          // 2 KB
    __shared__ float s_gi[4][3 * D];     // 6 KB
    __shared__ float s_gh[4][3 * D];     // 6 KB
    const int t = threadIdx.x;           // 0..383 == gate row
    const int b0 = blockIdx.x * 4;

    for (int i = t; i < 4 * 2 * D; i += 384) ((float*)s_q)[i] = qstar[(size_t)b0 * 2 * D + i];
    for (int i = t; i < 4 * D; i += 384)     ((float*)s_h)[i] = h[(size_t)b0 * D + i];
    __syncthreads();

    float gi[4], gh[4];
#pragma unroll
    for (int g = 0; g < 4; ++g) { gi[g] = bih[t]; gh[g] = bhh[t]; }

    const float4* Wr = (const float4*)(Wih + (size_t)t * (2 * D));
    for (int k4 = 0; k4 < (2 * D) / 4; ++k4) {
        float4 w = Wr[k4];
#pragma unroll
        for (int g = 0; g < 4; ++g) {
            float4 q = *(const float4*)&s_q[g][k4 * 4];
            gi[g] = fmaf(w.x, q.x, fmaf(w.y, q.y, fmaf(w.z, q.z, fmaf(w.w, q.w, gi[g]))));
        }
    }
    const float4* Vr = (const float4*)(Whh + (size_t)t * D);
    for (int k4 = 0; k4 < D / 4; ++k4) {
        float4 w = Vr[k4];
#pragma unroll
        for (int g = 0; g < 4; ++g) {
            float4 hh = *(const float4*)&s_h[g][k4 * 4];
            gh[g] = fmaf(w.x, hh.x, fmaf(w.y, hh.y, fmaf(w.z, hh.z, fmaf(w.w, hh.w, gh[g]))));
        }
    }
#pragma unroll
    for (int g = 0; g < 4; ++g) { s_gi[g][t] = gi[g]; s_gh[g][t] = gh[g]; }
    __syncthreads();

    if (t < D) {
#pragma unroll
        for (int g = 0; g < 4; ++g) {
            float r  = sigmoidf_(s_gi[g][t]         + s_gh[g][t]);
            float z  = sigmoidf_(s_gi[g][D + t]     + s_gh[g][D + t]);
            float nn = tanhf    (s_gi[g][2 * D + t] + r * s_gh[g][2 * D + t]);
            float hn = (1.f - z) * nn + z * s_h[g][t];
            h[(size_t)(b0 + g) * D + t] = hn;
            qstar[(size_t)(b0 + g) * 2 * D + t] = hn;   // q part of output
        }
    }
}

// ---------------------------------------------------------------------------
// K2: segment-softmax attention, SINGLE PASS (flash-style online softmax with
// rescaled weighted accumulator). One block per graph, 1024 threads
// (32 half-waves, 16 waves) -> 2 blocks/CU = full occupancy.
// Per half-wave per node: float4/lane dot + 5-step xor reduce, then
//   nm = max(m, p); scale = exp(m-nm); a = exp(p-nm);
//   l = l*scale + a; acc = acc*scale + a*x.
// Combine across half-waves via LDS with per-half-wave exp(m_hw - M) factors.
// No e_buf, x read exactly once.
// ---------------------------------------------------------------------------
__global__ __launch_bounds__(1024) void k_attn(const float* __restrict__ x,
        const float* __restrict__ h, const int* __restrict__ seg,
        float* qstar) {
    const int b = blockIdx.x;
    const int start = seg[b], end = seg[b + 1];
    const int tid = threadIdx.x;
    const int lane32 = tid & 31;
    const int hw = tid >> 5;          // half-wave id 0..31

    const float4 qf = ((const float4*)(h + (size_t)b * D))[lane32];

    float m_run = -INFINITY, l_run = 0.f;
    float4 acc = {0.f, 0.f, 0.f, 0.f};
    for (int node = start + hw; node < end; node += 32) {
        float4 xv = ((const float4*)(x + (size_t)node * D))[lane32];
        float p = fmaf(xv.x, qf.x, fmaf(xv.y, qf.y, fmaf(xv.z, qf.z, xv.w * qf.w)));
        p += __shfl_xor(p, 16, 64);
        p += __shfl_xor(p, 8, 64);
        p += __shfl_xor(p, 4, 64);
        p += __shfl_xor(p, 2, 64);
        p += __shfl_xor(p, 1, 64);
        float nm = fmaxf(m_run, p);
        float scale = __expf(m_run - nm);   // 0 on first iter (m_run = -inf)
        float a = __expf(p - nm);
        l_run = fmaf(l_run, scale, a);
        acc.x = fmaf(acc.x, scale, a * xv.x);
        acc.y = fmaf(acc.y, scale, a * xv.y);
        acc.z = fmaf(acc.z, scale, a * xv.z);
        acc.w = fmaf(acc.w, scale, a * xv.w);
        m_run = nm;
    }

    __shared__ float sm[32], sl[32];
    __shared__ float s_M, s_inv;
    if (lane32 == 0) { sm[hw] = m_run; sl[hw] = l_run; }
    __syncthreads();
    if (tid == 0) {
        float M = -INFINITY;
        for (int i = 0; i < 32; ++i) M = fmaxf(M, sm[i]);
        float L = 0.f;
        for (int i = 0; i < 32; ++i)
            L += (sm[i] == -INFINITY) ? 0.f : sl[i] * __expf(sm[i] - M);
        s_M = M;
        s_inv = 1.f / (L + 1e-16f);
    }
    __syncthreads();
    const float M = s_M;
    const float inv = s_inv;

    // rescale this half-wave's accumulator to the global max
    // guard: empty half-wave (m_run = -inf) must contribute exactly 0,
    // and empty graph (M = -inf) would give exp(-inf - -inf) = nan.
    const float fac = (m_run == -INFINITY) ? 0.f : __expf(m_run - M);
    acc.x *= fac; acc.y *= fac; acc.z *= fac; acc.w *= fac;

    // fold upper half-wave onto lower within each 64-lane wave
    acc.x += __shfl_down(acc.x, 32, 64);
    acc.y += __shfl_down(acc.y, 32, 64);
    acc.z += __shfl_down(acc.z, 32, 64);
    acc.w += __shfl_down(acc.w, 32, 64);

    __shared__ float rpart[16][D];    // 8 KB
    const int wave = tid >> 6;        // 0..15
    const int lane64 = tid & 63;
    if (lane64 < 32) ((float4*)rpart[wave])[lane64] = acc;
    __syncthreads();
    if (tid < D) {
        float v = 0.f;
#pragma unroll
        for (int w = 0; w < 16; ++w) v += rpart[w][tid];
        qstar[(size_t)b * (2 * D) + D + tid] = v * inv;   // r part of output
    }
}

// ---------------------------------------------------------------------------
extern "C" void kernel_launch(void* const* d_in, const int* in_sizes, int n_in,
                              void* d_out, int out_size, void* d_ws, size_t ws_size,
                              hipStream_t stream) {
    const float* x    = (const float*)d_in[0];
    const int*   batch= (const int*)d_in[1];
    // d_in[2] = batch_size scalar (fixed at B=512 compile time)
    const float* Wih  = (const float*)d_in[3];
    const float* Whh  = (const float*)d_in[4];
    const float* bih  = (const float*)d_in[5];
    const float* bhh  = (const float*)d_in[6];
    const int n = in_sizes[0] / D;        // 200000

    float* qstar = (float*)d_out;         // [B, 2D] — doubles as iteration state
    // every element of d_out is written each call (q by k_gru, r by k_attn,
    // incl. empty graphs) -> no d_out memset needed.

    // workspace layout: seg (4 KB) | h (256 KB)
    char* ws = (char*)d_ws;
    int*   seg   = (int*)ws;
    float* h     = (float*)(ws + 4096);

    hipMemsetAsync(h, 0, (size_t)B * D * sizeof(float), stream);
    k_bounds<<<(B + 256) / 256, 256, 0, stream>>>(batch, n, seg);

    for (int s = 0; s < STEPS; ++s) {
        k_gru<<<B / 4, 384, 0, stream>>>(qstar, h, Wih, Whh, bih, bhh);
        k_attn<<<B, 1024, 0, stream>>>(x, h, seg, qstar);
    }
}

// Round 4
// 250.839 us; speedup vs baseline: 1.5976x; 1.0985x over previous
//
#include <hip/hip_runtime.h>
#include <math.h>

constexpr int D = 128;       // in_channels
constexpr int B = 512;       // batch_size (graphs)
constexpr int STEPS = 3;
constexpr int NW_IH = 3 * D * 2 * D;   // 98304 elems, Wih [3D][2D]
constexpr int NW_HH = 3 * D * D;       // 49152 elems, Whh [3D][D]

__device__ __forceinline__ float sigmoidf_(float x) { return 1.f / (1.f + __expf(-x)); }
// bf16 pair unpack from a uint: low halfword / high halfword -> float (exact)
__device__ __forceinline__ float bflo(unsigned int u) { return __uint_as_float(u << 16); }
__device__ __forceinline__ float bfhi(unsigned int u) { return __uint_as_float(u & 0xffff0000u); }
__device__ __forceinline__ unsigned short f2bf_rn(float f) {
    unsigned int u = __float_as_uint(f);
    u += 0x7fffu + ((u >> 16) & 1u);    // round-to-nearest-even
    return (unsigned short)(u >> 16);
}

// ---------------------------------------------------------------------------
// K0 (prep): weights fp32 -> bf16 (RN), plus segment bounds via binary search
// on sorted batch[] (seg[g] = first index with batch[i] >= g).
// ---------------------------------------------------------------------------
__global__ __launch_bounds__(256) void k_prep(const float* __restrict__ Wih,
        const float* __restrict__ Whh, const int* __restrict__ batch, int n,
        unsigned short* __restrict__ wih_bf, unsigned short* __restrict__ whh_bf,
        int* __restrict__ seg) {
    int i = blockIdx.x * blockDim.x + threadIdx.x;
    if (i < NW_IH) wih_bf[i] = f2bf_rn(Wih[i]);
    else if (i < NW_IH + NW_HH) whh_bf[i - NW_IH] = f2bf_rn(Whh[i - NW_IH]);
    if (i <= B) {
        int lo = 0, hi = n;
        while (lo < hi) { int mid = (lo + hi) >> 1; if (batch[mid] < i) lo = mid + 1; else hi = mid; }
        seg[i] = lo;
    }
}

// ---------------------------------------------------------------------------
// K1 (fused Set2Set): one block per graph, 1024 threads, all 3 steps inside.
// State (h, q_star) lives in LDS; no global intermediates, no grid sync needed
// because the recurrence is fully independent per graph.
//   GRU:  threads 0..383 each compute one gate row (bf16 weights, 16B chunks,
//         L1/L2-served); epilogue threads 0..127 produce h_new.
//   Attn: flash-style single pass, 32 half-waves, float4/lane, 5-step xor
//         reduce, online (m,l,acc) with rescaling; combine via LDS.
// __launch_bounds__(1024,8): VGPR<=64 -> 2 blocks/CU = 32 waves/CU.
// ---------------------------------------------------------------------------
__global__ __launch_bounds__(1024, 8) void k_set2set(
        const float* __restrict__ x,
        const unsigned short* __restrict__ wih_bf,
        const unsigned short* __restrict__ whh_bf,
        const float* __restrict__ bih, const float* __restrict__ bhh,
        const int* __restrict__ seg, float* __restrict__ out) {
    __shared__ float s_q[2 * D];          // q_star for this graph: [q | r]
    __shared__ float s_h[D];
    __shared__ float s_gi[3 * D], s_gh[3 * D];
    __shared__ float sm[32], sl[32];
    __shared__ float s_M, s_inv;
    __shared__ float rpart[16][D];        // 8 KB

    const int b = blockIdx.x;
    const int tid = threadIdx.x;
    const int start = seg[b], end = seg[b + 1];
    const int lane32 = tid & 31;
    const int hw = tid >> 5;              // half-wave id 0..31

    if (tid < 2 * D) s_q[tid] = 0.f;
    if (tid < D) s_h[tid] = 0.f;
    __syncthreads();

    for (int step = 0; step < STEPS; ++step) {
        // ---- GRU gate rows ----
        if (tid < 3 * D) {
            const int t = tid;
            float gi = bih[t], gh = bhh[t];
            const uint4* wr = (const uint4*)(wih_bf + (size_t)t * (2 * D));
#pragma unroll 2
            for (int c = 0; c < (2 * D) / 8; ++c) {
                uint4 w = wr[c];
                const float* q = &s_q[c * 8];
                gi = fmaf(bflo(w.x), q[0], gi); gi = fmaf(bfhi(w.x), q[1], gi);
                gi = fmaf(bflo(w.y), q[2], gi); gi = fmaf(bfhi(w.y), q[3], gi);
                gi = fmaf(bflo(w.z), q[4], gi); gi = fmaf(bfhi(w.z), q[5], gi);
                gi = fmaf(bflo(w.w), q[6], gi); gi = fmaf(bfhi(w.w), q[7], gi);
            }
            const uint4* vr = (const uint4*)(whh_bf + (size_t)t * D);
#pragma unroll 2
            for (int c = 0; c < D / 8; ++c) {
                uint4 w = vr[c];
                const float* hh = &s_h[c * 8];
                gh = fmaf(bflo(w.x), hh[0], gh); gh = fmaf(bfhi(w.x), hh[1], gh);
                gh = fmaf(bflo(w.y), hh[2], gh); gh = fmaf(bfhi(w.y), hh[3], gh);
                gh = fmaf(bflo(w.z), hh[4], gh); gh = fmaf(bfhi(w.z), hh[5], gh);
                gh = fmaf(bflo(w.w), hh[6], gh); gh = fmaf(bfhi(w.w), hh[7], gh);
            }
            s_gi[t] = gi; s_gh[t] = gh;
        }
        __syncthreads();
        // ---- GRU epilogue ----
        if (tid < D) {
            const int t = tid;
            float r  = sigmoidf_(s_gi[t] + s_gh[t]);
            float z  = sigmoidf_(s_gi[D + t] + s_gh[D + t]);
            float nn = tanhf(s_gi[2 * D + t] + r * s_gh[2 * D + t]);
            float hn = (1.f - z) * nn + z * s_h[t];
            s_h[t] = hn;
            s_q[t] = hn;                  // q part of q_star
        }
        __syncthreads();

        // ---- flash attention over this graph's node range ----
        const float4 qf = *(const float4*)&s_h[lane32 * 4];
        float m_run = -INFINITY, l_run = 0.f;
        float4 acc = {0.f, 0.f, 0.f, 0.f};
        for (int node = start + hw; node < end; node += 32) {
            float4 xv = ((const float4*)(x + (size_t)node * D))[lane32];
            float p = fmaf(xv.x, qf.x, fmaf(xv.y, qf.y, fmaf(xv.z, qf.z, xv.w * qf.w)));
            p += __shfl_xor(p, 16, 64);
            p += __shfl_xor(p, 8, 64);
            p += __shfl_xor(p, 4, 64);
            p += __shfl_xor(p, 2, 64);
            p += __shfl_xor(p, 1, 64);
            float nm = fmaxf(m_run, p);
            float scale = __expf(m_run - nm);   // 0 on first iter
            float a = __expf(p - nm);
            l_run = fmaf(l_run, scale, a);
            acc.x = fmaf(acc.x, scale, a * xv.x);
            acc.y = fmaf(acc.y, scale, a * xv.y);
            acc.z = fmaf(acc.z, scale, a * xv.z);
            acc.w = fmaf(acc.w, scale, a * xv.w);
            m_run = nm;
        }
        if (lane32 == 0) { sm[hw] = m_run; sl[hw] = l_run; }
        __syncthreads();
        if (tid == 0) {
            float M = -INFINITY;
            for (int i = 0; i < 32; ++i) M = fmaxf(M, sm[i]);
            float L = 0.f;
            for (int i = 0; i < 32; ++i)
                L += (sm[i] == -INFINITY) ? 0.f : sl[i] * __expf(sm[i] - M);
            s_M = M;
            s_inv = 1.f / (L + 1e-16f);
        }
        __syncthreads();
        // rescale to global max; empty half-wave / empty graph -> exactly 0
        const float fac = (m_run == -INFINITY) ? 0.f : __expf(m_run - s_M);
        acc.x *= fac; acc.y *= fac; acc.z *= fac; acc.w *= fac;
        // fold upper half-wave onto lower within each 64-lane wave
        acc.x += __shfl_down(acc.x, 32, 64);
        acc.y += __shfl_down(acc.y, 32, 64);
        acc.z += __shfl_down(acc.z, 32, 64);
        acc.w += __shfl_down(acc.w, 32, 64);
        const int wave = tid >> 6;        // 0..15
        const int lane64 = tid & 63;
        if (lane64 < 32) ((float4*)rpart[wave])[lane64] = acc;
        __syncthreads();
        if (tid < D) {
            float v = 0.f;
#pragma unroll
            for (int w = 0; w < 16; ++w) v += rpart[w][tid];
            s_q[D + tid] = v * s_inv;     // r part of q_star
        }
        __syncthreads();                  // s_q complete for next GRU / output
    }

    // ---- write q_star row (s_q is exactly [q | r]) ----
    if (tid < 2 * D) out[(size_t)b * (2 * D) + tid] = s_q[tid];
}

// ---------------------------------------------------------------------------
extern "C" void kernel_launch(void* const* d_in, const int* in_sizes, int n_in,
                              void* d_out, int out_size, void* d_ws, size_t ws_size,
                              hipStream_t stream) {
    const float* x    = (const float*)d_in[0];
    const int*   batch= (const int*)d_in[1];
    // d_in[2] = batch_size scalar (fixed at B=512 compile time)
    const float* Wih  = (const float*)d_in[3];
    const float* Whh  = (const float*)d_in[4];
    const float* bih  = (const float*)d_in[5];
    const float* bhh  = (const float*)d_in[6];
    const int n = in_sizes[0] / D;        // 200000

    // workspace: seg (4 KB pad) | wih_bf (192 KB) | whh_bf (96 KB)
    char* ws = (char*)d_ws;
    int* seg = (int*)ws;
    unsigned short* wih_bf = (unsigned short*)(ws + 4096);
    unsigned short* whh_bf = (unsigned short*)(ws + 4096 + (size_t)NW_IH * 2);

    const int total = NW_IH + NW_HH;      // 147456 >= B+1, covers seg too
    k_prep<<<(total + 255) / 256, 256, 0, stream>>>(Wih, Whh, batch, n, wih_bf, whh_bf, seg);
    k_set2set<<<B, 1024, 0, stream>>>(x, wih_bf, whh_bf, bih, bhh, seg, (float*)d_out);
}